// Round 7
// baseline (30.150 us; speedup 1.0000x reference)
//
#include <hip/hip_runtime.h>
#include <math.h>

// Effective math (cross-attn K/V rows identical per batch element ->
// softmax uniform -> ctx == v; self-attn and QK paths are dead):
//   x   = im_repr @ ca_wv + ca_bv                  [256,768]
//   h   = gelu(x @ fi_w1 + fi_b1)  (exact erf)     [256,256]
//   y   = x + h @ fi_w2 + fi_b2                    [256,768]
//   out = LN(y) * ln_g + ln_b
//
// Round-6: kA converts w2 -> transposed bf16 in ws (prologue, no extra
// launch); kB reads w2T as uint4 (8 bf16 per 16B load) -> 8x fewer load
// instructions, 2x fewer bytes on the dominant stream.

#define DMODEL 768
#define ENCD   128
#define HID    256

// ws layout (bytes):
//   x   [256][768]  f32  @ 0
//   p   [6][256][256] f32 @ 786432
//   w2T [768][256]  bf16 @ 2359296
#define WS_X_OFF   0
#define WS_P_OFF   786432
#define WS_W2T_OFF 2359296
#define WS_NEED    2752512

__device__ __forceinline__ float gelu_exact(float v) {
    return 0.5f * v * (1.f + erff(v * 0.70710678118654752f));
}
__device__ __forceinline__ unsigned short f2bf(float f) {
    unsigned u = __float_as_uint(f);
    u = (u + 0x7FFFu + ((u >> 16) & 1u)) >> 16;   // RNE
    return (unsigned short)u;
}
__device__ __forceinline__ float bflo(unsigned u) { return __uint_as_float(u << 16); }
__device__ __forceinline__ float bfhi(unsigned u) { return __uint_as_float(u & 0xFFFF0000u); }

// ---- kA: grid(6 kc, 128 rowpairs) x 256 thr ----
// prologue (CVT): convert w2 column gid -> w2T bf16
// stage1: x[r][kc*128+c] = im_row @ wv col  (k=128)
// stage2: p[kc][r][j]    = x_slice @ w1 k-slice
template<bool CVT>
__global__ __launch_bounds__(256) void kA(
    const float* __restrict__ im,   // [256,128]
    const float* __restrict__ wv,   // [128,768]
    const float* __restrict__ bv,   // [768]
    const float* __restrict__ w1,   // [768,256]
    const float* __restrict__ w2,   // [256,768]
    char* __restrict__ ws)
{
    __shared__ float im_s[2][ENCD];
    __shared__ float x_s[2][ENCD];
    const int t = threadIdx.x, kc = blockIdx.x, r0 = blockIdx.y * 2;

    if (CVT) {
        const int gid = blockIdx.y * 6 + blockIdx.x;     // 0..767 = w2 col
        unsigned short* w2T = (unsigned short*)(ws + WS_W2T_OFF);
        w2T[gid * HID + t] = f2bf(w2[t * DMODEL + gid]);
    }

    im_s[t >> 7][t & 127] = im[(r0 + (t >> 7)) * ENCD + (t & 127)];
    __syncthreads();

    // stage 1 (one output per thread)
    const int row = t >> 7, c = t & 127;
    const int col = kc * ENCD + c;
    {
        float a0 = 0.f, a1 = 0.f;
        #pragma unroll 8
        for (int e = 0; e < ENCD; e += 2) {
            a0 += im_s[row][e]     * wv[e * DMODEL + col];
            a1 += im_s[row][e + 1] * wv[(e + 1) * DMODEL + col];
        }
        float a = a0 + a1 + bv[col];
        float* x = (float*)(ws + WS_X_OFF);
        x[(r0 + row) * DMODEL + col] = a;
        x_s[row][c] = a;
    }
    __syncthreads();

    // stage 2 (j = t, 2 rows, 4 acc chains)
    {
        float c0 = 0.f, c1 = 0.f, c2 = 0.f, c3 = 0.f;
        const float* w1c = w1 + kc * ENCD * HID;
        #pragma unroll 8
        for (int k = 0; k < ENCD; k += 2) {
            float w0 = w1c[k * HID + t];
            float w1v = w1c[(k + 1) * HID + t];
            c0 += x_s[0][k] * w0;     c1 += x_s[1][k] * w0;
            c2 += x_s[0][k + 1] * w1v; c3 += x_s[1][k + 1] * w1v;
        }
        float* p = (float*)(ws + WS_P_OFF) + kc * (256 * HID);
        p[(r0 + 0) * HID + t] = c0 + c2;
        p[(r0 + 1) * HID + t] = c1 + c3;
    }
}

// ---- kB: grid(256 rows) x 768 thr ----
template<bool BF16>
__global__ __launch_bounds__(768) void kB(
    const float* __restrict__ b1,   // [256]
    const float* __restrict__ w2,   // [256,768] (fp32 fallback)
    const float* __restrict__ b2,   // [768]
    const float* __restrict__ gam,  // [768]
    const float* __restrict__ bet,  // [768]
    const char* __restrict__ ws,
    float* __restrict__ out)        // [256,768]
{
    __shared__ float h_s[HID];
    __shared__ float red[12][2];
    const int t = threadIdx.x, r = blockIdx.x;

    if (t < HID) {
        const float* p = (const float*)(ws + WS_P_OFF);
        float v = b1[t];
        #pragma unroll
        for (int kc = 0; kc < 6; ++kc)
            v += p[kc * (256 * HID) + r * HID + t];
        h_s[t] = gelu_exact(v);
    }
    __syncthreads();

    float a0 = 0.f, a1 = 0.f, a2 = 0.f, a3 = 0.f;
    if (BF16) {
        const uint4* wp = (const uint4*)((const unsigned short*)(ws + WS_W2T_OFF)
                                         + (size_t)t * HID);
        #pragma unroll 8
        for (int q = 0; q < 32; ++q) {
            uint4 u = wp[q];
            const int j = q * 8;
            a0 += h_s[j + 0] * bflo(u.x); a1 += h_s[j + 1] * bfhi(u.x);
            a2 += h_s[j + 2] * bflo(u.y); a3 += h_s[j + 3] * bfhi(u.y);
            a0 += h_s[j + 4] * bflo(u.z); a1 += h_s[j + 5] * bfhi(u.z);
            a2 += h_s[j + 6] * bflo(u.w); a3 += h_s[j + 7] * bfhi(u.w);
        }
    } else {
        #pragma unroll 16
        for (int j = 0; j < HID; j += 2) {
            a0 += h_s[j]     * w2[j * DMODEL + t];
            a1 += h_s[j + 1] * w2[(j + 1) * DMODEL + t];
        }
    }

    const float* x = (const float*)(ws + WS_X_OFF);
    float y = x[r * DMODEL + t] + b2[t] + ((a0 + a2) + (a1 + a3));

    // LayerNorm across 12 waves
    float s = y, q = y * y;
    #pragma unroll
    for (int off = 32; off > 0; off >>= 1) {
        s += __shfl_down(s, off);
        q += __shfl_down(q, off);
    }
    const int lane = t & 63, wave = t >> 6;
    if (lane == 0) { red[wave][0] = s; red[wave][1] = q; }
    __syncthreads();

    float ss = 0.f, qq = 0.f;
    #pragma unroll
    for (int w = 0; w < 12; ++w) { ss += red[w][0]; qq += red[w][1]; }
    float mu   = ss * (1.f / DMODEL);
    float rstd = rsqrtf(qq * (1.f / DMODEL) - mu * mu + 1e-12f);

    out[r * DMODEL + t] = (y - mu) * rstd * gam[t] + bet[t];
}

extern "C" void kernel_launch(void* const* d_in, const int* in_sizes, int n_in,
                              void* d_out, int out_size, void* d_ws, size_t ws_size,
                              hipStream_t stream) {
    const float* im  = (const float*)d_in[0];   // im_repr [256,128]
    const float* wv  = (const float*)d_in[13];  // ca_wv   [128,768]
    const float* bv  = (const float*)d_in[14];  // ca_bv   [768]
    const float* w1  = (const float*)d_in[16];  // fi_w1   [768,256]
    const float* b1  = (const float*)d_in[17];  // fi_b1   [256]
    const float* w2  = (const float*)d_in[18];  // fi_w2   [256,768]
    const float* b2  = (const float*)d_in[19];  // fi_b2   [768]
    const float* g   = (const float*)d_in[20];  // ln_g    [768]
    const float* bt  = (const float*)d_in[21];  // ln_b    [768]
    float* out = (float*)d_out;
    char*  ws  = (char*)d_ws;

    if (ws_size >= (size_t)WS_NEED) {
        kA<true ><<<dim3(6, 128), 256, 0, stream>>>(im, wv, bv, w1, w2, ws);
        kB<true ><<<dim3(256), 768, 0, stream>>>(b1, w2, b2, g, bt, ws, out);
    } else {
        kA<false><<<dim3(6, 128), 256, 0, stream>>>(im, wv, bv, w1, w2, ws);
        kB<false><<<dim3(256), 768, 0, stream>>>(b1, w2, b2, g, bt, ws, out);
    }
}

// Round 8
// 23.842 us; speedup vs baseline: 1.2646x; 1.2646x over previous
//
#include <hip/hip_runtime.h>
#include <math.h>

// Effective math (cross-attn K/V rows identical per batch element ->
// softmax uniform -> ctx == v; self-attn and QK paths are dead):
//   x   = im_repr @ ca_wv + ca_bv                  [256,768]
//   h   = gelu(x @ fi_w1 + fi_b1)  (exact erf)     [256,256]
//   y   = x + h @ fi_w2 + fi_b2                    [256,768]
//   out = LN(y) * ln_g + ln_b
//
// Round-7: revert bf16 (uncoalesced conversion + strip loads hurt).
// Attack L2 re-read amplification instead: rows-per-block up.
//  kA: grid(6 kc, 64 rowquads) x 256 thr — 4 rows/block
//      wv 48->24 MB, w1 96->48 MB
//  kB: grid(128 rowpairs) x 768 thr — 2 rows/block
//      w2 192->96 MB
// All loads stay fp32, perfectly coalesced; 2-4 FMA chains per load.

#define DMODEL 768
#define ENCD   128
#define HID    256
#define KW     128   // k-slice width in kA (DMODEL / 6)

// ws layout (floats)
#define WS_X 0                   // x [256][768]
#define WS_P (256 * DMODEL)      // p [6][256][256]

__device__ __forceinline__ float gelu_exact(float v) {
    return 0.5f * v * (1.f + erff(v * 0.70710678118654752f));
}

// ---- kA: x col-slice (k=128 over im@wv) -> LDS -> w1 partial, 4 rows ----
__global__ __launch_bounds__(256) void kA(
    const float* __restrict__ im,   // [256,128]
    const float* __restrict__ wv,   // [128,768]
    const float* __restrict__ bv,   // [768]
    const float* __restrict__ w1,   // [768,256]
    float* __restrict__ ws)
{
    __shared__ float im_s[4][ENCD];
    __shared__ float x_s[4][KW];
    const int t  = threadIdx.x;
    const int kc = blockIdx.x;
    const int r0 = blockIdx.y * 4;

    #pragma unroll
    for (int i = t; i < 4 * ENCD; i += 256)
        im_s[i >> 7][i & 127] = im[(r0 + (i >> 7)) * ENCD + (i & 127)];
    __syncthreads();

    // stage 1: thread (half, c) computes rows {2*half, 2*half+1} at col c
    const int half = t >> 7, c = t & 127;
    const int col  = kc * KW + c;
    {
        const int ra = 2 * half, rb = ra + 1;
        float a0 = 0.f, a1 = 0.f;
        #pragma unroll 16
        for (int e = 0; e < ENCD; ++e) {
            float w = wv[e * DMODEL + col];
            a0 += im_s[ra][e] * w;
            a1 += im_s[rb][e] * w;
        }
        float b = bv[col];
        a0 += b; a1 += b;
        ws[(r0 + ra) * DMODEL + col] = a0;
        ws[(r0 + rb) * DMODEL + col] = a1;
        x_s[ra][c] = a0;
        x_s[rb][c] = a1;
    }
    __syncthreads();

    // stage 2: j = t, 4 rows share each w1 load (4 chains)
    {
        float c0 = 0.f, c1 = 0.f, c2 = 0.f, c3 = 0.f;
        const float* w1c = w1 + kc * KW * HID;
        #pragma unroll 16
        for (int k = 0; k < KW; ++k) {
            float w = w1c[k * HID + t];
            c0 += x_s[0][k] * w;
            c1 += x_s[1][k] * w;
            c2 += x_s[2][k] * w;
            c3 += x_s[3][k] * w;
        }
        float* p = ws + WS_P + kc * (256 * HID);
        p[(r0 + 0) * HID + t] = c0;
        p[(r0 + 1) * HID + t] = c1;
        p[(r0 + 2) * HID + t] = c2;
        p[(r0 + 3) * HID + t] = c3;
    }
}

// ---- kB: 2 rows/block. h = gelu(sum p + b1); y = x + h@w2 + b2; LN ----
__global__ __launch_bounds__(768) void kB(
    const float* __restrict__ b1,   // [256]
    const float* __restrict__ w2,   // [256,768]
    const float* __restrict__ b2,   // [768]
    const float* __restrict__ gam,  // [768]
    const float* __restrict__ bet,  // [768]
    const float* __restrict__ ws,
    float* __restrict__ out)        // [256,768]
{
    __shared__ float h_s[2][HID];
    __shared__ float red[12][4];
    const int t = threadIdx.x, r0 = blockIdx.x * 2;

    if (t < 512) {
        const int row = t >> 8, j = t & 255;
        const float* p = ws + WS_P + (r0 + row) * HID + j;
        float v = b1[j];
        #pragma unroll
        for (int kc = 0; kc < 6; ++kc)
            v += p[kc * (256 * HID)];
        h_s[row][j] = gelu_exact(v);
    }
    __syncthreads();

    // y rows r0, r0+1 at col t; each w2 load feeds 2 chains x 2-unroll
    float a00 = 0.f, a01 = 0.f, a10 = 0.f, a11 = 0.f;
    #pragma unroll 16
    for (int j = 0; j < HID; j += 2) {
        float w0 = w2[j * DMODEL + t];
        float w1v = w2[(j + 1) * DMODEL + t];
        a00 += h_s[0][j] * w0;  a01 += h_s[0][j + 1] * w1v;
        a10 += h_s[1][j] * w0;  a11 += h_s[1][j + 1] * w1v;
    }
    float bb = b2[t];
    float y0 = ws[WS_X + (r0 + 0) * DMODEL + t] + bb + (a00 + a01);
    float y1 = ws[WS_X + (r0 + 1) * DMODEL + t] + bb + (a10 + a11);

    // dual-row LayerNorm across 12 waves
    float s0 = y0, q0 = y0 * y0, s1 = y1, q1 = y1 * y1;
    #pragma unroll
    for (int off = 32; off > 0; off >>= 1) {
        s0 += __shfl_down(s0, off);
        q0 += __shfl_down(q0, off);
        s1 += __shfl_down(s1, off);
        q1 += __shfl_down(q1, off);
    }
    const int lane = t & 63, wave = t >> 6;
    if (lane == 0) {
        red[wave][0] = s0; red[wave][1] = q0;
        red[wave][2] = s1; red[wave][3] = q1;
    }
    __syncthreads();

    float ss0 = 0.f, qq0 = 0.f, ss1 = 0.f, qq1 = 0.f;
    #pragma unroll
    for (int w = 0; w < 12; ++w) {
        ss0 += red[w][0]; qq0 += red[w][1];
        ss1 += red[w][2]; qq1 += red[w][3];
    }
    float mu0   = ss0 * (1.f / DMODEL);
    float rstd0 = rsqrtf(qq0 * (1.f / DMODEL) - mu0 * mu0 + 1e-12f);
    float mu1   = ss1 * (1.f / DMODEL);
    float rstd1 = rsqrtf(qq1 * (1.f / DMODEL) - mu1 * mu1 + 1e-12f);

    float gv = gam[t], bvv = bet[t];
    out[(r0 + 0) * DMODEL + t] = (y0 - mu0) * rstd0 * gv + bvv;
    out[(r0 + 1) * DMODEL + t] = (y1 - mu1) * rstd1 * gv + bvv;
}

extern "C" void kernel_launch(void* const* d_in, const int* in_sizes, int n_in,
                              void* d_out, int out_size, void* d_ws, size_t ws_size,
                              hipStream_t stream) {
    const float* im  = (const float*)d_in[0];   // im_repr [256,128]
    const float* wv  = (const float*)d_in[13];  // ca_wv   [128,768]
    const float* bv  = (const float*)d_in[14];  // ca_bv   [768]
    const float* w1  = (const float*)d_in[16];  // fi_w1   [768,256]
    const float* b1  = (const float*)d_in[17];  // fi_b1   [256]
    const float* w2  = (const float*)d_in[18];  // fi_w2   [256,768]
    const float* b2  = (const float*)d_in[19];  // fi_b2   [768]
    const float* g   = (const float*)d_in[20];  // ln_g    [768]
    const float* bt  = (const float*)d_in[21];  // ln_b    [768]
    float* out = (float*)d_out;
    float* ws  = (float*)d_ws;

    kA<<<dim3(6, 64), 256, 0, stream>>>(im, wv, bv, w1, ws);
    kB<<<dim3(128), 768, 0, stream>>>(b1, w2, b2, g, bt, ws, out);
}